// Round 10
// baseline (99.332 us; speedup 1.0000x reference)
//
#include <hip/hip_runtime.h>
#include <math.h>

// QLSTM via exact 12-string Heisenberg reduction (verified round 9),
// now with TWO interleaved element-chains per lane (4 elements/wave,
// 256 blocks).  The closed form needs only ~25 live constants, so dual
// chains fit comfortably in VGPRs (round 7's 2-chain attempt failed only
// because the 81-coeff tensor blew the register file).  Chain B's
// independent instructions fill chain A's dependency-latency bubbles:
// per-element step cost drops from chain-bound to issue-bound.
//
//   t_q = cos(y_q+phi_q), r_q = sin(y_q+phi_q)   [phi = layer-0 angles]
//   c_q = cos(psi_q),     s_q = sin(psi_q)       [psi = layer-1 angles]
//   e_0 = c1c2c3 t0t1t3 + c1c2s3 r0r1r3 + s1s2c3 t0r1r3 + s1s2s3 r0t1t3
//   e_1 = (c0c1 t0t2 + s0s1 r0r2) t3
//   e_2 = c0c1c2 t1t3 + c0s1s2 r1r3
//   e_3 = c0c1c2c3 t0t2 + s0s1c2c3 r0r2 + s0c1s2s3 t0r2 + c0s1s2s3 r0t2
//
// Layout: lane = wire/gate w [1:0], unit j [4:2], elem slot e [5];
// chain A = element blockIdx*4 + e, chain B = element blockIdx*4 + 2 + e.

#define NQ 4
#define NL 2
#define BB 1024
#define TT 64
#define FF 32
#define HH 8

typedef unsigned uv2 __attribute__((ext_vector_type(2)));

// DPP quad_perm broadcast of quad position (VALU cross-lane)
#define QUAD_BCAST(x, CTRL) \
    __int_as_float(__builtin_amdgcn_mov_dpp(__float_as_int(x), (CTRL), 0xf, 0xf, true))
// DPP row rotate (within 16-lane row)
#define ROW_ROR(x, N) \
    __int_as_float(__builtin_amdgcn_mov_dpp(__float_as_int(x), 0x120 + (N), 0xf, 0xf, true))
// ds_swizzle lane ^ 16 (fallback)
#define SWZ_X16(x) \
    __int_as_float(__builtin_amdgcn_ds_swizzle(__float_as_int(x), 0x401F))

#if __has_builtin(__builtin_amdgcn_permlane16_swap)
__device__ __forceinline__ float permx16(float s, int lane) {
    uv2 r = __builtin_amdgcn_permlane16_swap(__builtin_bit_cast(unsigned, s),
                                             __builtin_bit_cast(unsigned, s),
                                             false, false);
    unsigned pick = (lane & 16) ? r.x : r.y;
    return __builtin_bit_cast(float, pick);
}
#else
__device__ __forceinline__ float permx16(float s, int lane) {
    (void)lane;
    return SWZ_X16(s);
}
#endif

#define XSTRIDE 68   // floats; 272B rows: 16B-aligned, 2-way bank aliasing only

__global__ __launch_bounds__(64, 1)
void qlstm_hb2_kernel(const float* __restrict__ x,
                      const float* __restrict__ w_in,
                      const float* __restrict__ b_in,
                      const float* __restrict__ w_out,
                      const float* __restrict__ b_out,
                      const float* __restrict__ wq_f,
                      const float* __restrict__ wq_i,
                      const float* __restrict__ wq_u,
                      const float* __restrict__ wq_o,
                      const float* __restrict__ w_fc,
                      const float* __restrict__ b_fc,
                      float* __restrict__ out) {
    __shared__ __align__(16) float sXW[16 * XSTRIDE];   // [(ee*4+w)][t]

    const int lane = threadIdx.x;
    const int w    = lane & 3;          // gate id AND wire id for this lane
    const int j    = (lane >> 2) & 7;   // hidden unit owned by this lane
    const int e    = lane >> 5;         // element slot within half (0/1)

    // ---------------- P1: xw[(ee,w)][t] = b_in[w] + x[elem,t,:].w_in[w,8:] --
    {
        const float b0 = b_in[0], b1 = b_in[1], b2 = b_in[2], b3 = b_in[3];
        #pragma unroll
        for (int r = 0; r < 16; ++r) {
            int slot = lane + 64 * r;          // 0..1023 = ee(2) t(6) w(2)
            int ee = slot >> 8;
            int tt = (slot >> 2) & 63;
            int ww = slot & 3;
            const float* xr = x + ((size_t)(blockIdx.x * 4 + ee) * TT + tt) * FF;
            float bb = (ww == 0) ? b0 : (ww == 1) ? b1 : (ww == 2) ? b2 : b3;
            const float* wrow = w_in + ww * 40 + 8;
            float acc0 = bb, acc1 = 0.0f;
            #pragma unroll
            for (int k = 0; k < 8; k += 2) {
                float4 xa = *reinterpret_cast<const float4*>(xr + 4 * k);
                float4 xb = *reinterpret_cast<const float4*>(xr + 4 * k + 4);
                acc0 = fmaf(xa.x, wrow[4*k+0],
                       fmaf(xa.y, wrow[4*k+1],
                       fmaf(xa.z, wrow[4*k+2],
                       fmaf(xa.w, wrow[4*k+3], acc0))));
                acc1 = fmaf(xb.x, wrow[4*k+4],
                       fmaf(xb.y, wrow[4*k+5],
                       fmaf(xb.z, wrow[4*k+6],
                       fmaf(xb.w, wrow[4*k+7], acc1))));
            }
            sXW[(ee * 4 + ww) * XSTRIDE + tt] = acc0 + acc1;
        }
    }
    __syncthreads();

    // ---------------- per-lane closed-form circuit constants ----------------
    const float* wq = (w == 0) ? wq_f : (w == 1) ? wq_i : (w == 2) ? wq_u : wq_o;
    const float cph0 = __cosf(wq[0]), sph0 = __sinf(wq[0]);
    const float cph1 = __cosf(wq[1]), sph1 = __sinf(wq[1]);
    const float cph2 = __cosf(wq[2]), sph2 = __sinf(wq[2]);
    const float cph3 = __cosf(wq[3]), sph3 = __sinf(wq[3]);
    const float c0 = __cosf(wq[4]), s0 = __sinf(wq[4]);
    const float c1 = __cosf(wq[5]), s1 = __sinf(wq[5]);
    const float c2 = __cosf(wq[6]), s2 = __sinf(wq[6]);
    const float c3 = __cosf(wq[7]), s3 = __sinf(wq[7]);
    const float wo0 = w_out[j * 4 + 0], wo1 = w_out[j * 4 + 1];
    const float wo2 = w_out[j * 4 + 2], wo3 = w_out[j * 4 + 3];
    const float g0a = wo0 * (c1 * c2 * c3);       // * t0 * P   (P = t1 t3)
    const float g0b = wo0 * (c1 * c2 * s3);       // * r0 * Q   (Q = r1 r3)
    const float g0c = wo0 * (s1 * s2 * c3);       // * t0 * Q
    const float g0d = wo0 * (s1 * s2 * s3);       // * r0 * P
    const float g1a = wo1 * (c0 * c1);            // * S * t3   (S = t0 t2)
    const float g1b = wo1 * (s0 * s1);            // * T * t3   (T = r0 r2)
    const float g2a = wo2 * (c0 * c1 * c2);       // * P
    const float g2b = wo2 * (c0 * s1 * s2);       // * Q
    const float g3a = wo3 * (c0 * c1 * c2 * c3);  // * S
    const float g3b = wo3 * (s0 * s1 * c2 * c3);  // * T
    const float g3c = wo3 * (s0 * c1 * s2 * s3);  // * U   (U = t0 r2)
    const float g3d = wo3 * (c0 * s1 * s2 * s3);  // * V   (V = r0 t2)
    const float bo  = b_out[j];

    const float wh  = w_in[w * 40 + j];
    const float wfc = w_fc[j];
    const bool  isG  = (w == 2);
    const float inS  = isG ? 2.0f : 1.0f;
    const float outS = isG ? 2.0f : 1.0f;
    const float outB = isG ? -1.0f : 0.0f;

    const float* pA = sXW + ((e)     * 4 + w) * XSTRIDE;   // element base+e
    const float* pB = sXW + ((e + 2) * 4 + w) * XSTRIDE;   // element base+2+e

    float ccA = 0.0f, hhA = 0.0f, ccB = 0.0f, hhB = 0.0f;

#define STEP(xwv, cc, hh) do {                                                \
    float p_ = (hh) * wh;                                                     \
    float s_ = p_ + ROW_ROR(p_, 4);                                           \
    s_ = s_ + ROW_ROR(s_, 8);                                                 \
    const float y_ = (xwv) + s_ + permx16(s_, lane);                          \
    const float u_ = __cosf(y_), v_ = __sinf(y_);                             \
    const float u0_ = QUAD_BCAST(u_, 0x00), u1_ = QUAD_BCAST(u_, 0x55);       \
    const float u2_ = QUAD_BCAST(u_, 0xAA), u3_ = QUAD_BCAST(u_, 0xFF);       \
    const float v0_ = QUAD_BCAST(v_, 0x00), v1_ = QUAD_BCAST(v_, 0x55);       \
    const float v2_ = QUAD_BCAST(v_, 0xAA), v3_ = QUAD_BCAST(v_, 0xFF);       \
    const float t0_ = fmaf(cph0, u0_, -(sph0 * v0_));                         \
    const float t1_ = fmaf(cph1, u1_, -(sph1 * v1_));                         \
    const float t2_ = fmaf(cph2, u2_, -(sph2 * v2_));                         \
    const float t3_ = fmaf(cph3, u3_, -(sph3 * v3_));                         \
    const float r0_ = fmaf(sph0, u0_, cph0 * v0_);                            \
    const float r1_ = fmaf(sph1, u1_, cph1 * v1_);                            \
    const float r2_ = fmaf(sph2, u2_, cph2 * v2_);                            \
    const float r3_ = fmaf(sph3, u3_, cph3 * v3_);                            \
    const float P_ = t1_ * t3_;                                               \
    const float Q_ = r1_ * r3_;                                               \
    const float S_ = t0_ * t2_;                                               \
    const float T_ = r0_ * r2_;                                               \
    const float U_ = t0_ * r2_;                                               \
    const float V_ = r0_ * t2_;                                               \
    const float mP_ = fmaf(g0a, t0_, fmaf(g0d, r0_, g2a));                    \
    const float mQ_ = fmaf(g0c, t0_, fmaf(g0b, r0_, g2b));                    \
    float a_ = fmaf(mP_, P_, fmaf(mQ_, Q_, bo));                              \
    const float e1_ = fmaf(g1a, S_, g1b * T_);                                \
    a_ = fmaf(e1_, t3_, a_);                                                  \
    a_ = fmaf(g3a, S_, a_);                                                   \
    a_ = fmaf(g3b, T_, a_);                                                   \
    a_ = fmaf(g3c, U_, a_);                                                   \
    a_ = fmaf(g3d, V_, a_);                                                   \
    const float sg_ = __builtin_amdgcn_rcpf(1.0f + __expf(-inS * a_));        \
    const float act_ = fmaf(sg_, outS, outB);                                 \
    const float fv_ = QUAD_BCAST(act_, 0x00), iv_ = QUAD_BCAST(act_, 0x55);   \
    const float gv_ = QUAD_BCAST(act_, 0xAA), ov_ = QUAD_BCAST(act_, 0xFF);   \
    (cc) = fmaf(fv_, (cc), iv_ * gv_);                                        \
    const float th_ = fmaf(2.0f,                                              \
        __builtin_amdgcn_rcpf(1.0f + __expf(-2.0f * (cc))), -1.0f);           \
    (hh) = ov_ * th_;                                                         \
} while (0)

    float4 xqA = *reinterpret_cast<const float4*>(pA);
    float4 xqB = *reinterpret_cast<const float4*>(pB);
    #pragma unroll 1
    for (int g4 = 0; g4 < 16; ++g4) {
        const int nx = (g4 < 15) ? (g4 + 1) * 4 : 60;   // clamp (discarded)
        float4 xqAn = *reinterpret_cast<const float4*>(pA + nx);
        float4 xqBn = *reinterpret_cast<const float4*>(pB + nx);
        STEP(xqA.x, ccA, hhA); STEP(xqB.x, ccB, hhB);
        STEP(xqA.y, ccA, hhA); STEP(xqB.y, ccB, hhB);
        STEP(xqA.z, ccA, hhA); STEP(xqB.z, ccB, hhB);
        STEP(xqA.w, ccA, hhA); STEP(xqB.w, ccB, hhB);
        xqA = xqAn; xqB = xqBn;
    }
#undef STEP

    // ---------------- epilogue: out = h.w_fc + b_fc -------------------------
    float pfA = hhA * wfc;
    float sfA = pfA + ROW_ROR(pfA, 4);
    sfA = sfA + ROW_ROR(sfA, 8);
    sfA = sfA + permx16(sfA, lane);
    float pfB = hhB * wfc;
    float sfB = pfB + ROW_ROR(pfB, 4);
    sfB = sfB + ROW_ROR(sfB, 8);
    sfB = sfB + permx16(sfB, lane);
    if ((lane & 31) == 0) {
        const int base = blockIdx.x * 4 + e;
        out[base]     = sfA + b_fc[0];
        out[base + 2] = sfB + b_fc[0];
    }
}

extern "C" void kernel_launch(void* const* d_in, const int* in_sizes, int n_in,
                              void* d_out, int out_size, void* d_ws, size_t ws_size,
                              hipStream_t stream) {
    const float* x     = (const float*)d_in[0];
    const float* w_in  = (const float*)d_in[1];
    const float* b_in  = (const float*)d_in[2];
    const float* w_out = (const float*)d_in[3];
    const float* b_out = (const float*)d_in[4];
    const float* wq_f  = (const float*)d_in[5];
    const float* wq_i  = (const float*)d_in[6];
    const float* wq_u  = (const float*)d_in[7];
    const float* wq_o  = (const float*)d_in[8];
    const float* w_fc  = (const float*)d_in[9];
    const float* b_fc  = (const float*)d_in[10];
    float* out = (float*)d_out;
    (void)in_sizes; (void)n_in; (void)out_size; (void)d_ws; (void)ws_size;

    qlstm_hb2_kernel<<<BB / 4, 64, 0, stream>>>(x, w_in, b_in, w_out, b_out,
                                                wq_f, wq_i, wq_u, wq_o,
                                                w_fc, b_fc, out);
}

// Round 11
// 90.884 us; speedup vs baseline: 1.0930x; 1.0930x over previous
//
#include <hip/hip_runtime.h>
#include <math.h>

// QLSTM via exact 12-string Heisenberg reduction (verified round 9).
// Round-11 = round-9 config (512 blocks, 2 elems/wave in lane halves --
// max wave count; round-10 showed wave count beats per-wave ILP here)
// + balanced-tree pre-activation accumulation (6-deep serial FMA chain
// -> 3-level tree) + pre-negated sin constants.
//
//   t_q = cos(y_q+phi_q), r_q = sin(y_q+phi_q)   [phi = layer-0 angles]
//   c_q = cos(psi_q),     s_q = sin(psi_q)       [psi = layer-1 angles]
//   e_0 = c1c2c3 t0t1t3 + c1c2s3 r0r1r3 + s1s2c3 t0r1r3 + s1s2s3 r0t1t3
//   e_1 = (c0c1 t0t2 + s0s1 r0r2) t3
//   e_2 = c0c1c2 t1t3 + c0s1s2 r1r3
//   e_3 = c0c1c2c3 t0t2 + s0s1c2c3 r0r2 + s0c1s2s3 t0r2 + c0s1s2s3 r0t2
//
// Layout: 32 lanes/element, lane = wire/gate w [1:0], unit j [4:2],
// element e [5]; 2 elements/wave, 512 blocks.

#define NQ 4
#define NL 2
#define BB 1024
#define TT 64
#define FF 32
#define HH 8

typedef unsigned uv2 __attribute__((ext_vector_type(2)));

// DPP quad_perm broadcast of quad position (VALU cross-lane)
#define QUAD_BCAST(x, CTRL) \
    __int_as_float(__builtin_amdgcn_mov_dpp(__float_as_int(x), (CTRL), 0xf, 0xf, true))
// DPP row rotate (within 16-lane row)
#define ROW_ROR(x, N) \
    __int_as_float(__builtin_amdgcn_mov_dpp(__float_as_int(x), 0x120 + (N), 0xf, 0xf, true))
// ds_swizzle lane ^ 16 (fallback)
#define SWZ_X16(x) \
    __int_as_float(__builtin_amdgcn_ds_swizzle(__float_as_int(x), 0x401F))

#if __has_builtin(__builtin_amdgcn_permlane16_swap)
__device__ __forceinline__ float permx16(float s, int lane) {
    uv2 r = __builtin_amdgcn_permlane16_swap(__builtin_bit_cast(unsigned, s),
                                             __builtin_bit_cast(unsigned, s),
                                             false, false);
    unsigned pick = (lane & 16) ? r.x : r.y;
    return __builtin_bit_cast(float, pick);
}
#else
__device__ __forceinline__ float permx16(float s, int lane) {
    (void)lane;
    return SWZ_X16(s);
}
#endif

#define XSTRIDE 68   // floats; 272B rows: 16B-aligned, 2-way bank aliasing only

__global__ __launch_bounds__(64, 1)
void qlstm_hb3_kernel(const float* __restrict__ x,
                      const float* __restrict__ w_in,
                      const float* __restrict__ b_in,
                      const float* __restrict__ w_out,
                      const float* __restrict__ b_out,
                      const float* __restrict__ wq_f,
                      const float* __restrict__ wq_i,
                      const float* __restrict__ wq_u,
                      const float* __restrict__ wq_o,
                      const float* __restrict__ w_fc,
                      const float* __restrict__ b_fc,
                      float* __restrict__ out) {
    __shared__ __align__(16) float sXW[8 * XSTRIDE];   // [(e*4+w)][t]

    const int lane = threadIdx.x;
    const int w    = lane & 3;          // gate id AND wire id for this lane
    const int j    = (lane >> 2) & 7;   // hidden unit owned by this lane
    const int e    = lane >> 5;         // element slot (2 per block)

    // ---------------- P1: xw[(e,w)][t] = b_in[w] + x[elem,t,:].w_in[w,8:] ---
    {
        const float b0 = b_in[0], b1 = b_in[1], b2 = b_in[2], b3 = b_in[3];
        #pragma unroll
        for (int r = 0; r < 8; ++r) {
            int slot = lane + 64 * r;          // 0..511 = ee(1) t(6) w(2)
            int ee = slot >> 8;
            int tt = (slot >> 2) & 63;
            int ww = slot & 3;
            const float* xr = x + ((size_t)(blockIdx.x * 2 + ee) * TT + tt) * FF;
            float bb = (ww == 0) ? b0 : (ww == 1) ? b1 : (ww == 2) ? b2 : b3;
            const float* wrow = w_in + ww * 40 + 8;
            float acc0 = bb, acc1 = 0.0f;
            #pragma unroll
            for (int k = 0; k < 8; k += 2) {
                float4 xa = *reinterpret_cast<const float4*>(xr + 4 * k);
                float4 xb = *reinterpret_cast<const float4*>(xr + 4 * k + 4);
                acc0 = fmaf(xa.x, wrow[4*k+0],
                       fmaf(xa.y, wrow[4*k+1],
                       fmaf(xa.z, wrow[4*k+2],
                       fmaf(xa.w, wrow[4*k+3], acc0))));
                acc1 = fmaf(xb.x, wrow[4*k+4],
                       fmaf(xb.y, wrow[4*k+5],
                       fmaf(xb.z, wrow[4*k+6],
                       fmaf(xb.w, wrow[4*k+7], acc1))));
            }
            sXW[(ee * 4 + ww) * XSTRIDE + tt] = acc0 + acc1;
        }
    }
    __syncthreads();

    // ---------------- per-lane closed-form circuit constants ----------------
    const float* wq = (w == 0) ? wq_f : (w == 1) ? wq_i : (w == 2) ? wq_u : wq_o;
    const float cph0 = __cosf(wq[0]), nsph0 = -__sinf(wq[0]);
    const float cph1 = __cosf(wq[1]), nsph1 = -__sinf(wq[1]);
    const float cph2 = __cosf(wq[2]), nsph2 = -__sinf(wq[2]);
    const float cph3 = __cosf(wq[3]), nsph3 = -__sinf(wq[3]);
    const float sph0 = -nsph0, sph1 = -nsph1, sph2 = -nsph2, sph3 = -nsph3;
    const float c0 = __cosf(wq[4]), s0 = __sinf(wq[4]);
    const float c1 = __cosf(wq[5]), s1 = __sinf(wq[5]);
    const float c2 = __cosf(wq[6]), s2 = __sinf(wq[6]);
    const float c3 = __cosf(wq[7]), s3 = __sinf(wq[7]);
    const float wo0 = w_out[j * 4 + 0], wo1 = w_out[j * 4 + 1];
    const float wo2 = w_out[j * 4 + 2], wo3 = w_out[j * 4 + 3];
    const float g0a = wo0 * (c1 * c2 * c3);       // * t0 * P   (P = t1 t3)
    const float g0b = wo0 * (c1 * c2 * s3);       // * r0 * Q   (Q = r1 r3)
    const float g0c = wo0 * (s1 * s2 * c3);       // * t0 * Q
    const float g0d = wo0 * (s1 * s2 * s3);       // * r0 * P
    const float g1a = wo1 * (c0 * c1);            // * S * t3   (S = t0 t2)
    const float g1b = wo1 * (s0 * s1);            // * T * t3   (T = r0 r2)
    const float g2a = wo2 * (c0 * c1 * c2);       // * P
    const float g2b = wo2 * (c0 * s1 * s2);       // * Q
    const float g3a = wo3 * (c0 * c1 * c2 * c3);  // * S
    const float g3b = wo3 * (s0 * s1 * c2 * c3);  // * T
    const float g3c = wo3 * (s0 * c1 * s2 * s3);  // * U   (U = t0 r2)
    const float g3d = wo3 * (c0 * s1 * s2 * s3);  // * V   (V = r0 t2)
    const float bo  = b_out[j];

    const float wh  = w_in[w * 40 + j];
    const float wfc = w_fc[j];
    const bool  isG  = (w == 2);
    const float inS  = isG ? 2.0f : 1.0f;
    const float outS = isG ? 2.0f : 1.0f;
    const float outB = isG ? -1.0f : 0.0f;

    const float* sxw = sXW + (e * 4 + w) * XSTRIDE;

    float cc = 0.0f, hh = 0.0f;

#define STEP(xwv) do {                                                        \
    /* y_w = xw + sum_j w_in[w,j] h_j  (row-DPP + permlane^16, no DS) */      \
    float p_ = hh * wh;                                                       \
    float s_ = p_ + ROW_ROR(p_, 4);                                           \
    s_ = s_ + ROW_ROR(s_, 8);                                                 \
    const float y_ = ((xwv) + s_) + permx16(s_, lane);                        \
    const float u_ = __cosf(y_), v_ = __sinf(y_);                             \
    const float u0_ = QUAD_BCAST(u_, 0x00), u1_ = QUAD_BCAST(u_, 0x55);       \
    const float u2_ = QUAD_BCAST(u_, 0xAA), u3_ = QUAD_BCAST(u_, 0xFF);       \
    const float v0_ = QUAD_BCAST(v_, 0x00), v1_ = QUAD_BCAST(v_, 0x55);       \
    const float v2_ = QUAD_BCAST(v_, 0xAA), v3_ = QUAD_BCAST(v_, 0xFF);       \
    /* t_q = cos(y_q+phi_q), r_q = sin(y_q+phi_q) for THIS lane's gate */     \
    const float t0_ = fmaf(cph0, u0_, nsph0 * v0_);                           \
    const float t1_ = fmaf(cph1, u1_, nsph1 * v1_);                           \
    const float t2_ = fmaf(cph2, u2_, nsph2 * v2_);                           \
    const float t3_ = fmaf(cph3, u3_, nsph3 * v3_);                           \
    const float r0_ = fmaf(sph0, u0_, cph0 * v0_);                            \
    const float r1_ = fmaf(sph1, u1_, cph1 * v1_);                            \
    const float r2_ = fmaf(sph2, u2_, cph2 * v2_);                            \
    const float r3_ = fmaf(sph3, u3_, cph3 * v3_);                            \
    /* pair products */                                                       \
    const float P_ = t1_ * t3_;                                               \
    const float Q_ = r1_ * r3_;                                               \
    const float S_ = t0_ * t2_;                                               \
    const float T_ = r0_ * r2_;                                               \
    const float U_ = t0_ * r2_;                                               \
    const float V_ = r0_ * t2_;                                               \
    /* 12-term pre-activation, balanced tree */                               \
    const float mP_ = fmaf(g0a, t0_, fmaf(g0d, r0_, g2a));                    \
    const float mQ_ = fmaf(g0c, t0_, fmaf(g0b, r0_, g2b));                    \
    const float e1_ = fmaf(g1a, S_, g1b * T_);                                \
    const float aA_ = fmaf(mP_, P_, fmaf(mQ_, Q_, bo));                       \
    const float aB_ = fmaf(e1_, t3_, fmaf(g3a, S_, g3b * T_));                \
    const float aC_ = fmaf(g3c, U_, g3d * V_);                                \
    const float a_  = aA_ + (aB_ + aC_);                                      \
    /* activation (sigmoid; tanh = 2*sig(2a)-1 for gate u) */                 \
    const float sg_ = __builtin_amdgcn_rcpf(1.0f + __expf(-inS * a_));        \
    const float act_ = fmaf(sg_, outS, outB);                                 \
    const float fv_ = QUAD_BCAST(act_, 0x00), iv_ = QUAD_BCAST(act_, 0x55);   \
    const float gv_ = QUAD_BCAST(act_, 0xAA), ov_ = QUAD_BCAST(act_, 0xFF);   \
    cc = fmaf(fv_, cc, iv_ * gv_);                                            \
    const float th_ = fmaf(2.0f,                                              \
        __builtin_amdgcn_rcpf(1.0f + __expf(-2.0f * cc)), -1.0f);             \
    hh = ov_ * th_;                                                           \
} while (0)

    float4 xq = *reinterpret_cast<const float4*>(sxw);
    #pragma unroll 1
    for (int g4 = 0; g4 < 16; ++g4) {
        const int nx = (g4 < 15) ? (g4 + 1) * 4 : 60;   // clamp (discarded)
        float4 xqn = *reinterpret_cast<const float4*>(sxw + nx);
        STEP(xq.x);
        STEP(xq.y);
        STEP(xq.z);
        STEP(xq.w);
        xq = xqn;
    }
#undef STEP

    // ---------------- epilogue: out = h.w_fc + b_fc -------------------------
    float pf = hh * wfc;
    float sf = pf + ROW_ROR(pf, 4);
    sf = sf + ROW_ROR(sf, 8);
    sf = sf + permx16(sf, lane);
    if ((lane & 31) == 0) out[blockIdx.x * 2 + e] = sf + b_fc[0];
}

extern "C" void kernel_launch(void* const* d_in, const int* in_sizes, int n_in,
                              void* d_out, int out_size, void* d_ws, size_t ws_size,
                              hipStream_t stream) {
    const float* x     = (const float*)d_in[0];
    const float* w_in  = (const float*)d_in[1];
    const float* b_in  = (const float*)d_in[2];
    const float* w_out = (const float*)d_in[3];
    const float* b_out = (const float*)d_in[4];
    const float* wq_f  = (const float*)d_in[5];
    const float* wq_i  = (const float*)d_in[6];
    const float* wq_u  = (const float*)d_in[7];
    const float* wq_o  = (const float*)d_in[8];
    const float* w_fc  = (const float*)d_in[9];
    const float* b_fc  = (const float*)d_in[10];
    float* out = (float*)d_out;
    (void)in_sizes; (void)n_in; (void)out_size; (void)d_ws; (void)ws_size;

    qlstm_hb3_kernel<<<BB / 2, 64, 0, stream>>>(x, w_in, b_in, w_out, b_out,
                                                wq_f, wq_i, wq_u, wq_o,
                                                w_fc, b_fc, out);
}